// Round 1
// 528.250 us; speedup vs baseline: 1.0187x; 1.0187x over previous
//
#include <hip/hip_runtime.h>
#include <hip/hip_bf16.h>
#include <math.h>

typedef __attribute__((ext_vector_type(8))) short short8;   // 8 x bf16 (4 VGPRs)
typedef __attribute__((ext_vector_type(4))) float floatx4;  // MFMA C/D frag

static __device__ __forceinline__ unsigned short f2bf(float f) {
    unsigned int u = __float_as_uint(f);
    unsigned int r = (u + 0x7fffu + ((u >> 16) & 1u)) >> 16;   // RNE
    return (unsigned short)r;
}

// async 16B global -> LDS copy (lds dest = wave-uniform base + lane*16)
static __device__ __forceinline__ void g2l16(const void* g, void* l) {
    __builtin_amdgcn_global_load_lds(
        (const __attribute__((address_space(1))) unsigned int*)g,
        (__attribute__((address_space(3))) unsigned int*)l,
        16, 0, 0);
}

// ---------------------------------------------------------------------------
// Grouped bf16 MFMA GEMM, double-buffered, optional split-K.
//   C[M,N] = A[M,K] @ W[N,K]^T
// A either fp32 (converted during staging, with K zero-pad support) or bf16
// (async g2l16 path). W always bf16 (pre-converted).
// ksplit==1: epilogue applies optional bias + BN + ReLU, writes fp32/bf16.
// ksplit>1 : each k-chunk block atomicAdds its fp32 partial into Cf
//            (Cf must be pre-zeroed); BN+ReLU done by bn_finalize.
// Tiles: 128x128, 4 waves, each wave a 64x64 quadrant of 16x16x32 MFMAs.
// ---------------------------------------------------------------------------
struct GDesc {
    const float*          Af;    // fp32 A (or null)
    const unsigned short* Ab;    // bf16 A (or null)
    const unsigned short* W;     // bf16 W, row stride = K
    float*          Cf;          // fp32 out / partial accum (or null)
    unsigned short* Cb;          // bf16 out (or null)
    const float *bias, *g, *b, *m, *v;
    int M, N, K;                 // K = padded to mult of 32 (W stride, LDS tiles)
    int Kreal;                   // A row stride / true K (= K unless padded)
    int fuse;                    // 1: BN+ReLU (ksplit==1 only)
    int nbx;                     // N / 128
    int block0;                  // first flat block id of this group
    int nbb;                     // blocks per k-chunk = nbx * (M/128)
    int ksplit;                  // #k-chunks (1 = no split)
};
struct GArgs { GDesc g[3]; int n; };

__global__ __launch_bounds__(256)
void gemm_grouped(GArgs ga)
{
    __shared__ unsigned short As[2][4096];   // 128 rows x 32 k (bf16)
    __shared__ unsigned short Bs[2][4096];

    const int bid = blockIdx.x;
    int gi = 0;
    #pragma unroll
    for (int i = 1; i < 3; ++i)
        if (i < ga.n && bid >= ga.g[i].block0) gi = i;
    const GDesc d = ga.g[gi];

    int local = bid - d.block0;
    int kc = 0;
    int Kc = d.K;
    if (d.ksplit > 1) {
        Kc = d.K / d.ksplit;
        kc = local / d.nbb;
        local -= kc * d.nbb;
    }
    const int kbeg = kc * Kc;
    const int bx = local % d.nbx;
    const int by = local / d.nbx;
    const int row0 = by * 128;
    const int col0 = bx * 128;

    const int tid  = threadIdx.x;
    const int wave = tid >> 6;
    const int lane = tid & 63;
    const int qd   = lane >> 4;
    const int ln   = lane & 15;
    const int wr   = (wave >> 1) * 64;
    const int wc   = (wave & 1) * 64;

    // g2l16 chunk mapping: chunk c -> row c>>2, k-offset (c&3)*8
    const int c0 = wave * 128 + lane;
    const int c1 = c0 + 64;
    const int r0 = c0 >> 2, k0 = (c0 & 3) * 8;
    const int r1 = c1 >> 2, k1 = (c1 & 3) * 8;

    // fp32 staging mapping: pass p covers rows p*32..p*32+31
    const int sr = tid >> 3;          // 0..31
    const int sc = (tid & 7) * 4;     // 0,4,..,28

    const bool afp = (d.Af != nullptr);
    const int niter = Kc >> 5;

    floatx4 acc[4][4];
    #pragma unroll
    for (int i = 0; i < 4; ++i)
        #pragma unroll
        for (int j = 0; j < 4; ++j) acc[i][j] = (floatx4){0.f, 0.f, 0.f, 0.f};

    // ---- prologue: stage tile 0 into buffer 0 ----
    g2l16(d.W + (size_t)(col0 + r0) * d.K + kbeg + k0, &Bs[0][(size_t)wave * 1024]);
    g2l16(d.W + (size_t)(col0 + r1) * d.K + kbeg + k1, &Bs[0][(size_t)wave * 1024 + 512]);
    if (afp) {
        #pragma unroll
        for (int p = 0; p < 4; ++p) {
            float4 v = (kbeg + sc < d.Kreal)
                ? *(const float4*)(d.Af + (size_t)(row0 + p * 32 + sr) * d.Kreal + kbeg + sc)
                : (float4){0.f, 0.f, 0.f, 0.f};
            ushort4 o = { f2bf(v.x), f2bf(v.y), f2bf(v.z), f2bf(v.w) };
            *(ushort4*)&As[0][(p * 32 + sr) * 32 + sc] = o;
        }
    } else {
        g2l16(d.Ab + (size_t)(row0 + r0) * d.K + kbeg + k0, &As[0][(size_t)wave * 1024]);
        g2l16(d.Ab + (size_t)(row0 + r1) * d.K + kbeg + k1, &As[0][(size_t)wave * 1024 + 512]);
    }
    __syncthreads();

    int cur = 0;
    for (int it = 0; it < niter; ++it) {
        const int kk = it * 32;
        const int nxt = cur ^ 1;
        const bool pf = (it + 1 < niter);

        float4 areg[4];
        if (pf) {
            const int kg = kbeg + kk + 32;
            g2l16(d.W + (size_t)(col0 + r0) * d.K + kg + k0, &Bs[nxt][(size_t)wave * 1024]);
            g2l16(d.W + (size_t)(col0 + r1) * d.K + kg + k1, &Bs[nxt][(size_t)wave * 1024 + 512]);
            if (afp) {
                #pragma unroll
                for (int p = 0; p < 4; ++p)
                    areg[p] = (kg + sc < d.Kreal)
                        ? *(const float4*)(d.Af + (size_t)(row0 + p * 32 + sr) * d.Kreal + kg + sc)
                        : (float4){0.f, 0.f, 0.f, 0.f};
            } else {
                g2l16(d.Ab + (size_t)(row0 + r0) * d.K + kg + k0, &As[nxt][(size_t)wave * 1024]);
                g2l16(d.Ab + (size_t)(row0 + r1) * d.K + kg + k1, &As[nxt][(size_t)wave * 1024 + 512]);
            }
        }

        // ---- compute on current buffer ----
        short8 a[4], b[4];
        #pragma unroll
        for (int i = 0; i < 4; ++i)
            a[i] = *(const short8*)&As[cur][(wr + i * 16 + ln) * 32 + qd * 8];
        #pragma unroll
        for (int j = 0; j < 4; ++j)
            b[j] = *(const short8*)&Bs[cur][(wc + j * 16 + ln) * 32 + qd * 8];
        #pragma unroll
        for (int i = 0; i < 4; ++i)
            #pragma unroll
            for (int j = 0; j < 4; ++j)
                acc[i][j] = __builtin_amdgcn_mfma_f32_16x16x32_bf16(
                                a[i], b[j], acc[i][j], 0, 0, 0);

        if (pf && afp) {
            #pragma unroll
            for (int p = 0; p < 4; ++p) {
                ushort4 o = { f2bf(areg[p].x), f2bf(areg[p].y),
                              f2bf(areg[p].z), f2bf(areg[p].w) };
                *(ushort4*)&As[nxt][(p * 32 + sr) * 32 + sc] = o;
            }
        }
        __syncthreads();
        cur = nxt;
    }

    // ---- epilogue: C/D layout col = lane&15, row = quad*4 + reg ----
    if (d.ksplit > 1) {
        // fp32 partial accumulation; BN/ReLU deferred to bn_finalize
        #pragma unroll
        for (int j = 0; j < 4; ++j) {
            const int col = col0 + wc + j * 16 + ln;
            #pragma unroll
            for (int i = 0; i < 4; ++i) {
                #pragma unroll
                for (int r = 0; r < 4; ++r) {
                    const int row = row0 + wr + i * 16 + qd * 4 + r;
                    atomicAdd(&d.Cf[(size_t)row * d.N + col], acc[i][j][r]);
                }
            }
        }
        return;
    }

    #pragma unroll
    for (int j = 0; j < 4; ++j) {
        const int col = col0 + wc + j * 16 + ln;
        float add = d.bias ? d.bias[col] : 0.f;
        float scale = 1.f, shift = 0.f;
        if (d.fuse) {
            scale = d.g[col] * rsqrtf(d.v[col] + 1e-5f);
            shift = d.b[col] - d.m[col] * scale;
        }
        #pragma unroll
        for (int i = 0; i < 4; ++i) {
            #pragma unroll
            for (int r = 0; r < 4; ++r) {
                const int row = row0 + wr + i * 16 + qd * 4 + r;
                float vv = acc[i][j][r] + add;
                if (d.fuse) vv = fmaxf(vv * scale + shift, 0.f);
                if (d.Cf) d.Cf[(size_t)row * d.N + col] = vv;
                if (d.Cb) d.Cb[(size_t)row * d.N + col] = f2bf(vv);
            }
        }
    }
}

// ---------------------------------------------------------------------------
// One-shot weight conversion: all 7 weight matrices fp32 -> bf16 (fc padded)
// ---------------------------------------------------------------------------
struct WSeg { const float* src; unsigned short* dst; int Kreal; int Kp; };
struct WArgs { WSeg s[7]; int off[8]; };

__global__ __launch_bounds__(256)
void cvt_weights(WArgs wa)
{
    int i = blockIdx.x * 256 + threadIdx.x;
    if (i >= wa.off[7]) return;
    int s = 0;
    #pragma unroll
    for (int j = 1; j < 7; ++j) if (i >= wa.off[j]) s = j;
    const WSeg sg = wa.s[s];
    const int li = i - wa.off[s];
    const int r = li / sg.Kp, c = li - r * sg.Kp;
    sg.dst[li] = (c < sg.Kreal) ? f2bf(sg.src[(size_t)r * sg.Kreal + c])
                                : (unsigned short)0;
}

// ---------------------------------------------------------------------------
// BN + ReLU + bf16 convert over split-K fp32 partial sums (vec4 per thread)
// ---------------------------------------------------------------------------
struct FSeg { const float* src; unsigned short* dst;
              const float *g, *b, *m, *v; int N; };
struct FArgs { FSeg s[3]; int off[4]; };   // offsets in vec4 units

__global__ __launch_bounds__(256)
void bn_finalize(FArgs fa)
{
    int i = blockIdx.x * 256 + threadIdx.x;
    if (i >= fa.off[3]) return;
    int s = 0;
    #pragma unroll
    for (int j = 1; j < 3; ++j) if (i >= fa.off[j]) s = j;
    const FSeg sg = fa.s[s];
    const int li = i - fa.off[s];
    const int e = li * 4;
    const int col = e % sg.N;              // N % 4 == 0 -> cols col..col+3
    float4 vv = *(const float4*)(sg.src + e);
    ushort4 o;
    #pragma unroll
    for (int r = 0; r < 4; ++r) {
        float sc = sg.g[col + r] * rsqrtf(sg.v[col + r] + 1e-5f);
        float sh = sg.b[col + r] - sg.m[col + r] * sc;
        float x  = fmaxf((&vv.x)[r] * sc + sh, 0.f);
        ((unsigned short*)&o)[r] = f2bf(x);
    }
    *(ushort4*)(sg.dst + e) = o;
}

// ---------------------------------------------------------------------------
// Fused attention (per batch row): channel attn (N=10) + spatial conv k=7 +
// weighted sum over N -> xsum[b][688]
// ---------------------------------------------------------------------------
__global__ __launch_bounds__(256)
void attn_kernel(const float* __restrict__ obj, const float* __restrict__ bbox,
                 const float* __restrict__ word, const float* __restrict__ sen,
                 const float* __restrict__ bod,
                 const float* __restrict__ Wc1, const float* __restrict__ Wc2,
                 const float* __restrict__ Wsa,
                 float* __restrict__ xsum_out)
{
    const int b = blockIdx.x;
    const int tid = threadIdx.x;

    __shared__ float xs[10][688];
    __shared__ float s0[688], s1[688];
    __shared__ float avec[10], mvec[10], att[10];
    __shared__ float cw[14], c1[50], c2[50];

    if (tid < 14) cw[tid] = Wsa[tid];
    if (tid < 50) { c1[tid] = Wc1[tid]; c2[tid] = Wc2[tid]; }

    for (int n = 0; n < 10; ++n) {
        const float* o  = obj  + ((size_t)b * 10 + n) * 128;
        const float* bx = bbox + ((size_t)b * 10 + n) * 4;
        const float* w  = word + ((size_t)b * 10 + n) * 300;
        const float* s  = sen  + ((size_t)b * 10 + n) * 128;
        const float* bo = bod  + (size_t)b * 128;
        for (int c = tid; c < 688; c += 256) {
            float v;
            if      (c < 128) v = o[c];
            else if (c < 132) v = bx[c - 128];
            else if (c < 432) v = w[c - 132];
            else if (c < 560) v = s[c - 432];
            else              v = bo[c - 560];
            xs[n][c] = v;
        }
    }
    __syncthreads();

    if (tid < 10) {
        float sm = 0.f, mx = -INFINITY;
        for (int c = 0; c < 688; ++c) {
            float v = xs[tid][c];
            sm += v; mx = fmaxf(mx, v);
        }
        avec[tid] = sm * (1.f / 688.f);
        mvec[tid] = mx;
    }
    __syncthreads();

    if (tid == 0) {
        float ha[5], hm[5];
        #pragma unroll
        for (int i = 0; i < 5; ++i) {
            float sa_ = 0.f, sm_ = 0.f;
            #pragma unroll
            for (int j = 0; j < 10; ++j) {
                sa_ += c1[i * 10 + j] * avec[j];
                sm_ += c1[i * 10 + j] * mvec[j];
            }
            ha[i] = fmaxf(sa_, 0.f);
            hm[i] = fmaxf(sm_, 0.f);
        }
        #pragma unroll
        for (int j = 0; j < 10; ++j) {
            float v = 0.f;
            #pragma unroll
            for (int i = 0; i < 5; ++i) v += c2[j * 5 + i] * (ha[i] + hm[i]);
            att[j] = 1.f / (1.f + expf(-v));
        }
    }
    __syncthreads();

    for (int c = tid; c < 688; c += 256) {
        float sm = 0.f, mx = -INFINITY;
        #pragma unroll
        for (int n = 0; n < 10; ++n) {
            float v = xs[n][c] * att[n];
            xs[n][c] = v;
            sm += v; mx = fmaxf(mx, v);
        }
        s0[c] = sm * 0.1f;
        s1[c] = mx;
    }
    __syncthreads();

    for (int c = tid; c < 688; c += 256) {
        float sa = 0.f;
        #pragma unroll
        for (int j = 0; j < 7; ++j) {
            int cc = c + j - 3;
            if (cc >= 0 && cc < 688)
                sa += cw[j] * s0[cc] + cw[7 + j] * s1[cc];
        }
        float sig = 1.f / (1.f + expf(-sa));
        float sm = 0.f;
        #pragma unroll
        for (int n = 0; n < 10; ++n) sm += xs[n][c];
        xsum_out[(size_t)b * 688 + c] = sm * sig;
    }
}

// ---------------------------------------------------------------------------
extern "C" void kernel_launch(void* const* d_in, const int* in_sizes, int n_in,
                              void* d_out, int out_size, void* d_ws, size_t ws_size,
                              hipStream_t stream)
{
    const float* f_obj = (const float*)d_in[0];
    const float* bbox  = (const float*)d_in[1];
    const float* word  = (const float*)d_in[2];
    const float* sent  = (const float*)d_in[3];
    const float* body  = (const float*)d_in[4];
    const float* W1_o  = (const float*)d_in[5];
    const float* g_o = (const float*)d_in[6],  *b_o = (const float*)d_in[7];
    const float* m_o = (const float*)d_in[8],  *v_o = (const float*)d_in[9];
    const float* W2_o  = (const float*)d_in[10];
    const float* W1_s  = (const float*)d_in[11];
    const float* g_s = (const float*)d_in[12], *b_s = (const float*)d_in[13];
    const float* m_s = (const float*)d_in[14], *v_s = (const float*)d_in[15];
    const float* W2_s  = (const float*)d_in[16];
    const float* W1_b  = (const float*)d_in[17];
    const float* g_b = (const float*)d_in[18], *b_b = (const float*)d_in[19];
    const float* m_b = (const float*)d_in[20], *v_b = (const float*)d_in[21];
    const float* W2_b  = (const float*)d_in[22];
    const float* Wc1 = (const float*)d_in[23];
    const float* Wc2 = (const float*)d_in[24];
    const float* Wsa = (const float*)d_in[25];
    const float* Wf  = (const float*)d_in[26];
    const float* bf  = (const float*)d_in[27];
    const float* g_f = (const float*)d_in[28], *b_f = (const float*)d_in[29];
    const float* m_f = (const float*)d_in[30], *v_f = (const float*)d_in[31];
    float* out = (float*)d_out;

    // ---- workspace carve; total ~44.8 MB ----
    char* p = (char*)d_ws;
    unsigned short* w1s = (unsigned short*)p; p += 4194304;   // 512*4096
    unsigned short* w2s = (unsigned short*)p; p += 131072;    // 128*512
    unsigned short* w1o = (unsigned short*)p; p += 262144;    // 128*1024
    unsigned short* w2o = (unsigned short*)p; p += 32768;     // 128*128
    unsigned short* w1b = (unsigned short*)p; p += 1048576;   // 256*2048
    unsigned short* w2b = (unsigned short*)p; p += 65536;     // 128*256
    unsigned short* wfp = (unsigned short*)p; p += 360448;    // 256*704 padded
    unsigned short* h_s = (unsigned short*)p; p += 10485760;  // 10240*512
    unsigned short* h_o = (unsigned short*)p; p += 2621440;   // 10240*128
    unsigned short* h_b = (unsigned short*)p; p += 524288;    // 1024*256
    // split-K fp32 partial region; later aliased by stage-2/attn outputs
    // (partials are dead after bn_finalize, which runs before stage-2)
    char* region = p; p += 27262976;                          // 26 MB
    float* ps = (float*)region;                               // 10240*512 f32
    float* po = (float*)(region + 20971520);                  // 10240*128 f32
    float* pb = (float*)(region + 26214400);                  // 1024*256 f32
    float* sen_f  = (float*)region;                           // 10240*128 f32
    float* obj_f  = (float*)(region + 5242880);               // 10240*128 f32
    float* bod_f  = (float*)(region + 10485760);              // 1024*128 f32
    float* xsum_f = (float*)(region + 11010048);              // 1024*688 f32
    if ((size_t)(p - (char*)d_ws) > ws_size) return;

    // ---- 0) zero split-K accumulators ----
    hipMemsetAsync(region, 0, 27262976, stream);

    // ---- 1) weights -> bf16 in one launch ----
    WArgs wa;
    wa.s[0] = { W1_s, w1s, 4096, 4096 };
    wa.s[1] = { W2_s, w2s,  512,  512 };
    wa.s[2] = { W1_o, w1o, 1024, 1024 };
    wa.s[3] = { W2_o, w2o,  128,  128 };
    wa.s[4] = { W1_b, w1b, 2048, 2048 };
    wa.s[5] = { W2_b, w2b,  256,  256 };
    wa.s[6] = { Wf,   wfp,  688,  704 };
    const int wn[7] = { 512*4096, 128*512, 128*1024, 128*128, 256*2048, 128*256, 256*704 };
    wa.off[0] = 0;
    for (int i = 0; i < 7; ++i) wa.off[i + 1] = wa.off[i] + wn[i];
    cvt_weights<<<(wa.off[7] + 255) / 256, 256, 0, stream>>>(wa);

    // ---- 2) stage-1 grouped GEMM, split-K x2 (fp32 partials via atomicAdd)
    //      grid: sent 2*320 + obj 2*80 + body 2*16 = 832 blocks (~3.3/CU)
    {
        GArgs ga; ga.n = 3;
        ga.g[0] = { sent,  nullptr, w1s, ps, nullptr, nullptr, nullptr, nullptr, nullptr, nullptr,
                    10240, 512, 4096, 4096, 0, 4, 0,   320, 2 };
        ga.g[1] = { f_obj, nullptr, w1o, po, nullptr, nullptr, nullptr, nullptr, nullptr, nullptr,
                    10240, 128, 1024, 1024, 0, 1, 640, 80,  2 };
        ga.g[2] = { body,  nullptr, w1b, pb, nullptr, nullptr, nullptr, nullptr, nullptr, nullptr,
                    1024,  256, 2048, 2048, 0, 2, 800, 16,  2 };
        gemm_grouped<<<832, 256, 0, stream>>>(ga);
    }

    // ---- 2b) BN + ReLU + bf16 convert of partial sums -> h_s/h_o/h_b ----
    {
        FArgs fa;
        fa.s[0] = { ps, h_s, g_s, b_s, m_s, v_s, 512 };
        fa.s[1] = { po, h_o, g_o, b_o, m_o, v_o, 128 };
        fa.s[2] = { pb, h_b, g_b, b_b, m_b, v_b, 256 };
        fa.off[0] = 0;
        fa.off[1] = 10240 * 512 / 4;
        fa.off[2] = fa.off[1] + 10240 * 128 / 4;
        fa.off[3] = fa.off[2] + 1024 * 256 / 4;
        bn_finalize<<<(fa.off[3] + 255) / 256, 256, 0, stream>>>(fa);
    }

    // ---- 3) stage-2 grouped GEMM (bf16 A; fp32 out) ----
    {
        GArgs ga; ga.n = 3;
        ga.g[0] = { nullptr, h_s, w2s, sen_f, nullptr, nullptr, nullptr, nullptr, nullptr, nullptr,
                    10240, 128, 512, 512, 0, 1, 0,   80, 1 };
        ga.g[1] = { nullptr, h_o, w2o, obj_f, nullptr, nullptr, nullptr, nullptr, nullptr, nullptr,
                    10240, 128, 128, 128, 0, 1, 80,  80, 1 };
        ga.g[2] = { nullptr, h_b, w2b, bod_f, nullptr, nullptr, nullptr, nullptr, nullptr, nullptr,
                    1024,  128, 256, 256, 0, 1, 160, 8,  1 };
        gemm_grouped<<<168, 256, 0, stream>>>(ga);
    }

    // ---- 4) fused attention + sum over N ----
    attn_kernel<<<1024, 256, 0, stream>>>(obj_f, bbox, word, sen_f, bod_f,
                                          Wc1, Wc2, Wsa, xsum_f);

    // ---- 5) fc1 (+bias, BN, ReLU), K=688 zero-padded to 704 in staging ----
    {
        GArgs ga; ga.n = 1;
        ga.g[0] = { xsum_f, nullptr, wfp, out, nullptr, bf, g_f, b_f, m_f, v_f,
                    1024, 256, 704, 688, 1, 2, 0, 16, 1 };
        gemm_grouped<<<16, 256, 0, stream>>>(ga);
    }
}